// Round 3
// baseline (441.424 us; speedup 1.0000x reference)
//
#include <hip/hip_runtime.h>

// RandCropResize v6: multi-tile persistent-ish blocks + reg-double-buffered
// staging with a non-draining barrier.
// B=64, C=3, H=W=512, fp32. Each block owns TILES=8 consecutive (b,oy)
// tiles of ONE batch. Staging for tile i+1 is issued into registers BEFORE
// tile i's barrier; the barrier is raw s_barrier + lgkmcnt(0) only (no
// vmcnt drain -- prefetch goes to thread-private regs, so no cross-thread
// visibility is needed), so the global-load latency of tile i+1 hides under
// tile i's gather+store. x-coords/crop-span params depend only on b and are
// computed ONCE per block (v3-v5 recomputed them per output row).
// Gather arithmetic is bit-identical to v4 (absmax must stay 0.0078125).

#define BB 64
#define CC 3
#define HH 512
#define WW 512
#define NB (BB * HH)            // 32768 (b,oy) tiles
#define TILES 8
#define NBLK (NB / TILES)       // 4096 blocks
#define PITCH 516               // floats per LDS row; 516*4 % 16 == 0

// Barrier that does NOT drain vmcnt: LDS producer/consumer ordering only.
#define BAR() do { asm volatile("s_waitcnt lgkmcnt(0)" ::: "memory"); \
                   __builtin_amdgcn_s_barrier(); } while (0)

__global__ __launch_bounds__(256) void rand_crop_resize_kernel(
    const float* __restrict__ img,
    const int* __restrict__ y1a, const int* __restrict__ y2a,
    const int* __restrict__ x1a, const int* __restrict__ x2a,
    float* __restrict__ out)
{
    __shared__ float s[6 * PITCH];   // 6 raw rows: [c*2 + tap]

    // XCD swizzle; each block's 8 tiles stay inside one batch (512 % 8 == 0).
    const int j   = (blockIdx.x & 7) * (NBLK / 8) + (blockIdx.x >> 3);
    const int r0  = j * TILES;
    const int b   = r0 >> 9;
    const int oy0 = r0 & (HH - 1);

    const int Y1 = y1a[b], Y2 = y2a[b], X1 = x1a[b], X2 = x2a[b];
    const int   ny_i = Y2 - Y1;
    const float nyf  = (float)ny_i;

    const int t  = threadIdx.x;
    const int g  = t >> 7;          // 0/1: stages rows 0-2 / 3-5
    const int tt = t & 127;         // chunk lane within a row

    // ---- crop-span chunk range (uniform per block) ----
    const int nx_i = X2 - X1;
    const int c0   = X1 >> 2;
    const int c1   = min((X1 + nx_i) >> 2, (WW >> 2) - 1);
    const int nch  = c1 - c0 + 1;
    const int xoff = X1 - (c0 << 2);
    const int zi   = xoff + nx_i;   // one-past slot, <= 515

    // Dead slot: read only when wx == 0; when X1+nx == 512 it is never
    // staged (would be an OOB global read), so the zero persists. When
    // X1+nx < 512 staging overwrites it with real (finite) data each tile.
    if (t < 6) s[t * PITCH + zi] = 0.0f;

    // ---- x coords: computed ONCE per block, reused for all TILES rows ----
    const float nx = (float)nx_i, nxm1f = nx - 1.0f;
    int ixk[2]; float wxk[2];
    #pragma unroll
    for (int k = 0; k < 2; ++k) {
        const int ox = 2 * t + k;
        float sx = ((float)ox + 0.5f) * nx * (1.0f / 512.0f) - 0.5f;
        sx = fminf(fmaxf(sx, 0.0f), nxm1f);
        const int ix0 = (int)sx;     // sx >= 0, trunc == floor
        wxk[k] = sx - (float)ix0;
        ixk[k] = xoff + ix0;         // local LDS index; ix+1 <= zi
    }

    const size_t base = (size_t)b * (size_t)(CC * HH * WW);

    auto ycoord = [&](int oy, int& iy0, int& iy1, float& wy) {
        float sy = ((float)oy + 0.5f) * nyf * (1.0f / 512.0f) - 0.5f;
        sy = fminf(fmaxf(sy, 0.0f), nyf - 1.0f);
        const int i0 = (int)sy;      // sy >= 0, trunc == floor
        wy  = sy - (float)i0;
        iy1 = min(i0 + 1, ny_i - 1) + Y1;
        iy0 = i0 + Y1;
    };

    auto issue = [&](int iy0t, int iy1t, float4* buf) {
        if (tt < nch) {
            #pragma unroll
            for (int k = 0; k < 3; ++k) {
                const int rw = 3 * g + k;                // 0..5
                const int c  = rw >> 1;
                const int iy = (rw & 1) ? iy1t : iy0t;
                buf[k] = ((const float4*)(img + base
                             + (size_t)(c * HH + iy) * (size_t)WW))[c0 + tt];
            }
        }
    };

    auto commit = [&](const float4* buf) {
        if (tt < nch) {
            #pragma unroll
            for (int k = 0; k < 3; ++k)
                ((float4*)(s + (3 * g + k) * PITCH))[tt] = buf[k];
        }
    };

    auto gather = [&](int oy, float wy) {
        float2 res[3];
        #pragma unroll
        for (int k = 0; k < 2; ++k) {
            const int   ix = ixk[k];
            const float wx = wxk[k];
            #pragma unroll
            for (int c = 0; c < 3; ++c) {
                const float* s0 = s + (2 * c) * PITCH;
                const float* s1 = s0 + PITCH;
                const float v00 = s0[ix];
                const float v01 = s0[ix + 1];    // ds_read2_b32
                const float v10 = s1[ix];
                const float v11 = s1[ix + 1];
                const float r0v = v00 + (v10 - v00) * wy;
                const float r1v = v01 + (v11 - v01) * wy;
                const float v   = r0v + (r1v - r0v) * wx;
                if (k == 0) res[c].x = v; else res[c].y = v;
            }
        }
        #pragma unroll
        for (int c = 0; c < 3; ++c) {
            float2* orow = (float2*)(out
                + ((size_t)(b * CC + c) * (size_t)HH + (size_t)oy) * (size_t)WW);
            orow[t] = res[c];
        }
    };

    // ---- software pipeline over TILES tiles, reg double-buffer A/B ----
    float4 A[3] = {}, B[3] = {};
    int iy0t, iy1t; float wyA, wyB;

    ycoord(oy0, iy0t, iy1t, wyA);
    issue(iy0t, iy1t, A);

    #pragma unroll
    for (int itp = 0; itp < TILES; itp += 2) {
        // tile itp (data in A)
        commit(A);                               // waits vmcnt for A only
        ycoord(oy0 + itp + 1, iy0t, iy1t, wyB);
        issue(iy0t, iy1t, B);                    // prefetch crosses barrier
        BAR();
        gather(oy0 + itp, wyA);
        BAR();

        // tile itp+1 (data in B)
        commit(B);
        if (itp + 2 < TILES) {
            ycoord(oy0 + itp + 2, iy0t, iy1t, wyA);
            issue(iy0t, iy1t, A);
        }
        BAR();
        gather(oy0 + itp + 1, wyB);
        BAR();
    }
}

extern "C" void kernel_launch(void* const* d_in, const int* in_sizes, int n_in,
                              void* d_out, int out_size, void* d_ws, size_t ws_size,
                              hipStream_t stream) {
    const float* img = (const float*)d_in[0];
    const int*   y1  = (const int*)d_in[1];
    const int*   y2  = (const int*)d_in[2];
    const int*   x1  = (const int*)d_in[3];
    const int*   x2  = (const int*)d_in[4];
    float*       out = (float*)d_out;

    dim3 grid(NBLK);    // 4096 blocks x 8 tiles
    dim3 block(256);
    hipLaunchKernelGGL(rand_crop_resize_kernel, grid, block, 0, stream,
                       img, y1, y2, x1, x2, out);
}

// Round 4
// 323.796 us; speedup vs baseline: 1.3633x; 1.3633x over previous
//
#include <hip/hip_runtime.h>

// RandCropResize v7: v4 structure (proven 320.8 us) + direct global->LDS
// staging via __builtin_amdgcn_global_load_lds (width 16).
// B=64, C=3, H=W=512, fp32. One block per (b, oy): stages the 6 bilinear
// source rows (2 y-taps x 3 channels, crop-span only) straight into LDS --
// no VGPR round-trip, no ds_write, no lgkm chain; __syncthreads' vmcnt(0)
// drain is the only wait, hidden by ~8 resident blocks/CU.
// LDS-dest constraint (wave-uniform base + lane*16) is satisfied: per wave,
// g = t>>7 and (tt >= 64) are wave-uniform, so dest = rw*2064 + 16*tt is
// base(uniform) + lane*16.  Gather arithmetic bit-identical to v4
// (absmax must stay 0.0078125).

#define BB 64
#define CC 3
#define HH 512
#define WW 512
#define NB (BB * HH)          // 32768 blocks
#define PITCH 516             // floats per LDS row; 516*4 = 2064, %16 == 0

typedef const __attribute__((address_space(1))) void g_void;
typedef __attribute__((address_space(3))) void l_void;

__global__ __launch_bounds__(256) void rand_crop_resize_kernel(
    const float* __restrict__ img,
    const int* __restrict__ y1a, const int* __restrict__ y2a,
    const int* __restrict__ x1a, const int* __restrict__ x2a,
    float* __restrict__ out)
{
    __shared__ float s[6 * PITCH];   // rows: [c*2 + tap], crop-span only

    // XCD swizzle: give XCD k a contiguous slice of 8 batches.
    const int r  = (blockIdx.x & 7) * (NB / 8) + (blockIdx.x >> 3);
    const int oy = r & (HH - 1);
    const int b  = r >> 9;

    const int Y1 = y1a[b], Y2 = y2a[b], X1 = x1a[b], X2 = x2a[b];

    // ---- y coords (uniform) ----
    const int ny_i = Y2 - Y1;
    float sy = ((float)oy + 0.5f) * (float)ny_i * (1.0f / 512.0f) - 0.5f;
    sy = fminf(fmaxf(sy, 0.0f), (float)ny_i - 1.0f);
    int iy0 = (int)sy;                       // sy >= 0, trunc == floor
    const int iy1 = min(iy0 + 1, ny_i - 1) + Y1;
    const float wy = sy - (float)iy0;
    iy0 += Y1;

    const int t = threadIdx.x;

    // ---- crop-span chunk range (uniform) ----
    const int nx_i = X2 - X1;
    const int c0   = X1 >> 2;                               // first float4 chunk
    const int c1   = min((X1 + nx_i) >> 2, (WW >> 2) - 1);  // last chunk <=127
    const int nch  = c1 - c0 + 1;                           // chunks/row <=128
    const int xoff = X1 - (c0 << 2);                        // = X1 & 3
    const int zi   = xoff + nx_i;                           // one-past slot <=515

    // Zero the dead slot of each row: read only when wx == 0. When X1+nx==512
    // it is never staged (would be OOB), so the zero persists; otherwise
    // staging may overwrite it with finite image data -- also fine (wx==0).
    if (t < 6) s[t * PITCH + zi] = 0.0f;

    // ---- stage 6 crop spans, direct global->LDS (no VGPR round-trip) ----
    const size_t base = (size_t)b * (size_t)(CC * HH * WW);
    const int g  = t >> 7;                   // 0/1: rows 0-2 / 3-5 (wave-uniform)
    const int tt = t & 127;                  // chunk lane within the row
    if (tt < nch) {
        #pragma unroll
        for (int k = 0; k < 3; ++k) {
            const int rw = 3 * g + k;        // 0..5
            const int c  = rw >> 1;
            const int iy = (rw & 1) ? iy1 : iy0;
            const float* gsrc = img + base
                + (size_t)(c * HH + iy) * (size_t)WW + (size_t)((c0 + tt) << 2);
            float* ldst = s + rw * PITCH + (tt << 2);
            __builtin_amdgcn_global_load_lds((g_void*)gsrc, (l_void*)ldst,
                                             16, 0, 0);
        }
    }
    __syncthreads();   // vmcnt(0) drain: LDS now holds the 6 rows

    // ---- x bilinear: 2 px/thread, coords shared across 3 channels ----
    const float nx    = (float)nx_i;
    const float nxm1f = nx - 1.0f;

    float2 res[3];
    #pragma unroll
    for (int k = 0; k < 2; ++k) {
        const int ox = 2 * t + k;
        float sx = ((float)ox + 0.5f) * nx * (1.0f / 512.0f) - 0.5f;
        sx = fminf(fmaxf(sx, 0.0f), nxm1f);
        const int   ix0 = (int)sx;           // sx >= 0, trunc == floor
        const float wx  = sx - (float)ix0;
        const int   ix  = xoff + ix0;        // local LDS index; ix+1 <= zi

        #pragma unroll
        for (int c = 0; c < 3; ++c) {
            const float* s0 = s + (2 * c) * PITCH;
            const float* s1 = s0 + PITCH;
            const float v00 = s0[ix];
            const float v01 = s0[ix + 1];    // fuses into ds_read2_b32
            const float v10 = s1[ix];
            const float v11 = s1[ix + 1];
            const float r0v = v00 + (v10 - v00) * wy;
            const float r1v = v01 + (v11 - v01) * wy;
            const float v   = r0v + (r1v - r0v) * wx;
            if (k == 0) res[c].x = v; else res[c].y = v;
        }
    }

    #pragma unroll
    for (int c = 0; c < 3; ++c) {
        float2* orow = (float2*)(out
            + ((size_t)(b * CC + c) * (size_t)HH + (size_t)oy) * (size_t)WW);
        orow[t] = res[c];
    }
}

extern "C" void kernel_launch(void* const* d_in, const int* in_sizes, int n_in,
                              void* d_out, int out_size, void* d_ws, size_t ws_size,
                              hipStream_t stream) {
    const float* img = (const float*)d_in[0];
    const int*   y1  = (const int*)d_in[1];
    const int*   y2  = (const int*)d_in[2];
    const int*   x1  = (const int*)d_in[3];
    const int*   x2  = (const int*)d_in[4];
    float*       out = (float*)d_out;

    dim3 grid(NB);      // 32768 blocks, one per (b, oy)
    dim3 block(256);
    hipLaunchKernelGGL(rand_crop_resize_kernel, grid, block, 0, stream,
                       img, y1, y2, x1, x2, out);
}

// Round 5
// 317.276 us; speedup vs baseline: 1.3913x; 1.0205x over previous
//
#include <hip/hip_runtime.h>

// RandCropResize v8: 4-row band tiles + direct global->LDS staging.
// B=64, C=3, H=W=512, fp32. One block per (b, band of 4 oy rows).
// Because sy advances by ny/512 < 1 per output row, 4 consecutive output
// rows touch at most 5 consecutive source rows per channel (iy1(oy+3) <=
// iy0(oy)+4). The block stages that [rlo, rhi] row range ONCE (crop-span
// chunks, global_load_lds width 16, per-wave half-row slots so the LDS
// dest is wave-uniform base + lane*16) and emits 4 output rows from it:
// ~1.7x structural fetch cut + 4x amortization of setup VALU + 4x fewer
// blocks. No per-thread addressable arrays (v6's scratch trap); gather
// arithmetic bit-identical to v4 (absmax must stay 0.0078125).

#define BB 64
#define CC 3
#define HH 512
#define WW 512
#define NB (BB * HH)            // 32768 (b,oy) tiles
#define TILES 4
#define NBAND (NB / TILES)      // 8192 blocks
#define NR 5                    // max source rows per channel per band
#define PITCH 516               // floats per LDS row; 516*4 % 16 == 0

typedef const __attribute__((address_space(1))) void g_void;
typedef __attribute__((address_space(3))) void l_void;

__global__ __launch_bounds__(256) void rand_crop_resize_kernel(
    const float* __restrict__ img,
    const int* __restrict__ y1a, const int* __restrict__ y2a,
    const int* __restrict__ x1a, const int* __restrict__ x2a,
    float* __restrict__ out)
{
    __shared__ float s[3 * NR * PITCH];   // 15 rows x 516 = 30.96 KB

    // XCD swizzle: consecutive bands of one batch stay on one XCD.
    const int j   = (blockIdx.x & 7) * (NBAND / 8) + (blockIdx.x >> 3);
    const int r0  = j * TILES;
    const int b   = r0 >> 9;
    const int oy0 = r0 & (HH - 1);

    const int Y1 = y1a[b], Y2 = y2a[b], X1 = x1a[b], X2 = x2a[b];
    const int   ny_i = Y2 - Y1;
    const float nyf  = (float)ny_i;

    const int t = threadIdx.x;

    // ---- y coords for the 4 rows (uniform; unrolled -> registers) ----
    int iy0q[TILES], iy1q[TILES]; float wyq[TILES];
    #pragma unroll
    for (int q = 0; q < TILES; ++q) {
        float syv = ((float)(oy0 + q) + 0.5f) * nyf * (1.0f / 512.0f) - 0.5f;
        syv = fminf(fmaxf(syv, 0.0f), nyf - 1.0f);
        const int i0 = (int)syv;             // syv >= 0, trunc == floor
        wyq[q]  = syv - (float)i0;
        iy1q[q] = min(i0 + 1, ny_i - 1) + Y1;
        iy0q[q] = i0 + Y1;
    }
    const int rlo   = iy0q[0];
    const int nrows = iy1q[TILES - 1] - rlo + 1;   // <= NR

    // ---- crop-span chunk range (uniform per block) ----
    const int nx_i = X2 - X1;
    const int c0   = X1 >> 2;                               // first chunk
    const int c1   = min((X1 + nx_i) >> 2, (WW >> 2) - 1);  // last chunk <=127
    const int nch  = c1 - c0 + 1;                           // chunks <=128
    const int xoff = X1 - (c0 << 2);                        // = X1 & 3
    const int zi   = xoff + nx_i;                           // dead slot <=515

    // Zero the dead slot of each LDS row: read only when wx == 0. When
    // X1+nx == 512 it is never staged (global load would be OOB) so the
    // zero persists; otherwise staging may overwrite it -- fine (wx==0).
    if (t < 3 * NR) s[t * PITCH + zi] = 0.0f;

    // ---- stage up to 15 crop-span rows, direct global->LDS ----
    // Half-row slots round-robined over waves: per issued op, row and h are
    // wave-uniform, so LDS dest = uniform base + lane*16.  ch<nch partial
    // exec mask is the v7-proven guard.
    const size_t base = (size_t)b * (size_t)(CC * HH * WW);
    const int wave = t >> 6;
    const int lane = t & 63;
    #pragma unroll
    for (int c = 0; c < 3; ++c) {
        #pragma unroll
        for (int rr = 0; rr < NR; ++rr) {
            #pragma unroll
            for (int h = 0; h < 2; ++h) {
                const int idx = (c * NR + rr) * 2 + h;   // compile-time
                if (((idx & 3) == wave) && rr < nrows) {
                    const int ch = h * 64 + lane;
                    if (ch < nch) {
                        const int iy = rlo + rr;         // <= Y1+ny-1 <= 511
                        const float* gsrc = img + base
                            + (size_t)(c * HH + iy) * (size_t)WW
                            + (size_t)((c0 + ch) << 2);
                        float* ldst = s + (c * NR + rr) * PITCH + (ch << 2);
                        __builtin_amdgcn_global_load_lds((g_void*)gsrc,
                                                         (l_void*)ldst,
                                                         16, 0, 0);
                    }
                }
            }
        }
    }
    __syncthreads();   // vmcnt+lgkm drain: LDS rows ready

    // ---- x coords: once per block, shared by all 4 rows x 3 channels ----
    const float nx = (float)nx_i, nxm1f = nx - 1.0f;
    int ixk[2]; float wxk[2];
    #pragma unroll
    for (int k = 0; k < 2; ++k) {
        const int ox = 2 * t + k;
        float sx = ((float)ox + 0.5f) * nx * (1.0f / 512.0f) - 0.5f;
        sx = fminf(fmaxf(sx, 0.0f), nxm1f);
        const int ix0 = (int)sx;             // sx >= 0, trunc == floor
        wxk[k] = sx - (float)ix0;
        ixk[k] = xoff + ix0;                 // LDS index; ix+1 <= zi
    }

    // ---- emit 4 output rows ----
    #pragma unroll
    for (int q = 0; q < TILES; ++q) {
        const int   r0q = iy0q[q] - rlo;     // 0..4 (uniform)
        const int   r1q = iy1q[q] - rlo;
        const float wy  = wyq[q];

        float2 res[3];
        #pragma unroll
        for (int k = 0; k < 2; ++k) {
            const int   ix = ixk[k];
            const float wx = wxk[k];
            #pragma unroll
            for (int c = 0; c < 3; ++c) {
                const float* s0 = s + (c * NR + r0q) * PITCH;
                const float* s1 = s + (c * NR + r1q) * PITCH;
                const float v00 = s0[ix];
                const float v01 = s0[ix + 1];    // ds_read2_b32
                const float v10 = s1[ix];
                const float v11 = s1[ix + 1];
                const float r0v = v00 + (v10 - v00) * wy;
                const float r1v = v01 + (v11 - v01) * wy;
                const float v   = r0v + (r1v - r0v) * wx;
                if (k == 0) res[c].x = v; else res[c].y = v;
            }
        }

        #pragma unroll
        for (int c = 0; c < 3; ++c) {
            float2* orow = (float2*)(out
                + ((size_t)(b * CC + c) * (size_t)HH + (size_t)(oy0 + q))
                  * (size_t)WW);
            orow[t] = res[c];
        }
    }
}

extern "C" void kernel_launch(void* const* d_in, const int* in_sizes, int n_in,
                              void* d_out, int out_size, void* d_ws, size_t ws_size,
                              hipStream_t stream) {
    const float* img = (const float*)d_in[0];
    const int*   y1  = (const int*)d_in[1];
    const int*   y2  = (const int*)d_in[2];
    const int*   x1  = (const int*)d_in[3];
    const int*   x2  = (const int*)d_in[4];
    float*       out = (float*)d_out;

    dim3 grid(NBAND);   // 8192 blocks x 4 output rows
    dim3 block(256);
    hipLaunchKernelGGL(rand_crop_resize_kernel, grid, block, 0, stream,
                       img, y1, y2, x1, x2, out);
}